// Round 1
// 183.238 us; speedup vs baseline: 1.0356x; 1.0356x over previous
//
#include <hip/hip_runtime.h>
#include <math.h>

// ---------------- problem constants ----------------
#define CIN   512
#define NOUT  123      // DEPTH + CT
#define DEPN  59
#define CT    64
#define B_    4
#define N_    6
#define FH    16
#define FW    44
#define HW    704      // FH*FW
#define NPIX  (B_*N_*HW)          // 16896
#define NX    128
#define BEV_ELEMS (B_*CT*NX*NX)   // 4,194,304
#define DEPTH_OFF BEV_ELEMS

// ws layout (float offsets). Double region first (8B aligned at base).
#define TDREC   40
#define WS_WB   1920                       // bf16 weight [128 o][512 c]
#define WS_PS   (WS_WB + 32768)            // p-slab  [row = bw*96 + n*16+h][64] (cols 0..58)
#define WS_FS   (WS_PS + NPIX*64)          // f-slab  [row][64]
#define WS_C    (WS_FS + NPIX*64)          // group sums [bw][59][64]
#define WS_VOX  (WS_C + B_*FW*DEPN*64)     // int [bw][59]

typedef short bf16x8 __attribute__((ext_vector_type(8)));
typedef float f32x4  __attribute__((ext_vector_type(4)));

__device__ inline unsigned short f2bf(float f) {   // RNE f32->bf16
    unsigned u = __float_as_uint(f);
    return (unsigned short)((u + 0x7fffu + ((u >> 16) & 1u)) >> 16);
}

// ---------------- K0: bf16 weight build + per-(b,n) f64 transforms ----------------
__device__ inline void inv3d(const double* m, double* o) {
    #pragma clang fp contract(off)
    double c00 = m[4]*m[8] - m[5]*m[7];
    double c01 = m[5]*m[6] - m[3]*m[8];
    double c02 = m[3]*m[7] - m[4]*m[6];
    double det = m[0]*c00 + m[1]*c01 + m[2]*c02;
    o[0] = c00/det; o[1] = (m[2]*m[7]-m[1]*m[8])/det; o[2] = (m[1]*m[5]-m[2]*m[4])/det;
    o[3] = c01/det; o[4] = (m[0]*m[8]-m[2]*m[6])/det; o[5] = (m[2]*m[3]-m[0]*m[5])/det;
    o[6] = c02/det; o[7] = (m[1]*m[6]-m[0]*m[7])/det; o[8] = (m[0]*m[4]-m[1]*m[3])/det;
}
__device__ inline void mm3d(const double* a, const double* b, double* o) {
    #pragma clang fp contract(off)
    for (int i = 0; i < 3; ++i)
        for (int k = 0; k < 3; ++k)
            o[i*3+k] = (a[i*3+0]*b[0*3+k] + a[i*3+1]*b[1*3+k]) + a[i*3+2]*b[2*3+k];
}

__global__ void k0_prep(const float* __restrict__ rots, const float* __restrict__ trans,
                        const float* __restrict__ intr, const float* __restrict__ prots,
                        const float* __restrict__ ptrans, const float* __restrict__ bda,
                        const float* __restrict__ W, float* __restrict__ ws) {
    int tid = blockIdx.x * 256 + threadIdx.x;
    int stride = gridDim.x * 256;
    unsigned short* wb = (unsigned short*)(ws + WS_WB);
    for (int i = tid; i < 128 * CIN; i += stride) {
        int o = i >> 9, c = i & 511;
        wb[i] = (o < NOUT) ? f2bf(W[o * CIN + c]) : (unsigned short)0;
    }
    if (blockIdx.x == 0 && threadIdx.x < B_ * N_) {
        #pragma clang fp contract(off)
        int t = threadIdx.x;
        int b = t / N_;
        double* X = (double*)(ws) + t * TDREC;
        double PR[9], Kd[9], Rd[9], Bd[9];
        for (int i = 0; i < 9; ++i) PR[i] = (double)prots[t * 9 + i];
        for (int i = 0; i < 9; ++i) Kd[i] = (double)intr[t * 9 + i];
        for (int i = 0; i < 9; ++i) Rd[i] = (double)rots[t * 9 + i];
        for (int i = 0; i < 9; ++i) Bd[i] = (double)bda[b * 9 + i];
        double iPR[9]; inv3d(PR, iPR);
        for (int i = 0; i < 9; ++i) X[i] = iPR[i];
        for (int i = 0; i < 3; ++i) X[9 + i] = (double)ptrans[t * 3 + i];
        double iK[9];  inv3d(Kd, iK);
        double comb[9]; mm3d(Rd, iK, comb);
        for (int i = 0; i < 9; ++i) X[12 + i] = comb[i];
        for (int i = 0; i < 3; ++i) X[21 + i] = (double)trans[t * 3 + i];
        for (int i = 0; i < 9; ++i) X[24 + i] = Bd[i];
    }
}

// ---------------- K1: bf16 MFMA GEMM + fused softmax epilogue ----------------
// Block: 64 pix x 128 o, 4 waves. v2: weight tile staged in LDS (shared across
// waves, was per-thread global reads = 64KB/block/K-iter), double-buffered LDS
// + register prefetch, ONE barrier per K-iter. Epilogue additionally writes the
// depth output directly (removes k2c's stride-256B p-slab gather).
__global__ __launch_bounds__(256) void k1_gemm(const float* __restrict__ x,
                                               const float* __restrict__ bias,
                                               float* __restrict__ ws,
                                               float* __restrict__ dout) {
    __shared__ unsigned short sxa[2][64][72];    // A tile bf16 [pix][c], padded
    __shared__ unsigned short swb[2][128][72];   // B tile bf16 [o][c], padded
    const int tid = threadIdx.x;
    const int wave = tid >> 6, lane = tid & 63;
    const int l15 = lane & 15, quad = lane >> 4;
    const int bn = blockIdx.y;
    const int pixbase = blockIdx.x * 64;
    const float* xg = x + (size_t)bn * CIN * HW + pixbase;
    const unsigned short* wbg = (const unsigned short*)(ws + WS_WB);
    const int cpack = tid >> 4;        // 0..15 (channel group of 4)
    const int pix4 = (tid & 15) * 4;   // pixel group of 4
    const int wo  = tid >> 3;          // weight-stage row   (0..31 per 256 chunk)
    const int wsub = tid & 7;          // weight-stage 16B sub-chunk

    f32x4 acc[8] = {};
    float4 r0, r1, r2, r3;             // prefetched x tile (4c x 4pix)
    uint4  w4[4];                      // prefetched weight tile chunks

    {   // prologue: loads for ck = 0
        const float* src = xg + (size_t)(4 * cpack) * HW + pix4;
        r0 = *(const float4*)(src);
        r1 = *(const float4*)(src + HW);
        r2 = *(const float4*)(src + 2 * HW);
        r3 = *(const float4*)(src + 3 * HW);
        #pragma unroll
        for (int i = 0; i < 4; ++i) {
            const int o = wo + 32 * i;
            w4[i] = *(const uint4*)(wbg + (size_t)o * CIN + wsub * 8);
        }
    }

    #pragma unroll
    for (int it = 0; it < 8; ++it) {
        const int buf = it & 1;
        {   // store staged regs -> LDS[buf] (waits the prefetch vmcnt)
            const float* f0 = (const float*)&r0; const float* f1 = (const float*)&r1;
            const float* f2 = (const float*)&r2; const float* f3 = (const float*)&r3;
            #pragma unroll
            for (int i = 0; i < 4; ++i) {
                uint2 pk;
                pk.x = (unsigned)f2bf(f0[i]) | ((unsigned)f2bf(f1[i]) << 16);
                pk.y = (unsigned)f2bf(f2[i]) | ((unsigned)f2bf(f3[i]) << 16);
                *(uint2*)&sxa[buf][pix4 + i][4 * cpack] = pk;
            }
            #pragma unroll
            for (int i = 0; i < 4; ++i)
                *(uint4*)&swb[buf][wo + 32 * i][wsub * 8] = w4[i];
        }
        if (it < 7) {   // prefetch next K-step (overlaps the MFMA phase below)
            const int ck = (it + 1) * 64;
            const float* src = xg + (size_t)(ck + 4 * cpack) * HW + pix4;
            r0 = *(const float4*)(src);
            r1 = *(const float4*)(src + HW);
            r2 = *(const float4*)(src + 2 * HW);
            r3 = *(const float4*)(src + 3 * HW);
            #pragma unroll
            for (int i = 0; i < 4; ++i) {
                const int o = wo + 32 * i;
                w4[i] = *(const uint4*)(wbg + (size_t)o * CIN + ck + wsub * 8);
            }
        }
        __syncthreads();   // single barrier: store(buf) visible; buf^1 free (last read 2 iters ago)
        #pragma unroll
        for (int ks = 0; ks < 64; ks += 32) {
            const bf16x8 a = *(const bf16x8*)&sxa[buf][wave * 16 + l15][ks + quad * 8];
            #pragma unroll
            for (int nt = 0; nt < 8; ++nt) {
                const bf16x8 b = *(const bf16x8*)&swb[buf][nt * 16 + l15][ks + quad * 8];
                acc[nt] = __builtin_amdgcn_mfma_f32_16x16x32_bf16(a, b, acc[nt], 0, 0, 0);
            }
        }
    }
    // epilogue: softmax + split store. D row = quad*4+reg (pix), col = l15 (o).
    const int b = bn / N_, n = bn - b * N_;
    float bb[8];
    #pragma unroll
    for (int nt = 0; nt < 8; ++nt) {
        int o = nt * 16 + l15;
        bb[nt] = (o < NOUT) ? bias[o] : 0.0f;
    }
    float* ps = ws + WS_PS;
    float* fs = ws + WS_FS;
    #pragma unroll
    for (int reg = 0; reg < 4; ++reg) {
        int pix = pixbase + wave * 16 + quad * 4 + reg;
        int h = pix / FW, w = pix - h * FW;
        size_t row = (size_t)(b * FW + w) * 96 + n * FH + h;
        float v[4]; float m = -INFINITY;
        #pragma unroll
        for (int nt = 0; nt < 4; ++nt) {
            v[nt] = acc[nt][reg] + bb[nt];
            if (nt * 16 + l15 < DEPN) m = fmaxf(m, v[nt]);
        }
        #pragma unroll
        for (int msk = 8; msk >= 1; msk >>= 1) m = fmaxf(m, __shfl_xor(m, msk, 64));
        float e[4], s = 0.0f;
        #pragma unroll
        for (int nt = 0; nt < 4; ++nt) {
            e[nt] = (nt * 16 + l15 < DEPN) ? expf(v[nt] - m) : 0.0f;
            s += e[nt];
        }
        #pragma unroll
        for (int msk = 8; msk >= 1; msk >>= 1) s += __shfl_xor(s, msk, 64);
        const float inv = 1.0f / s;
        #pragma unroll
        for (int nt = 0; nt < 4; ++nt) {
            int o = nt * 16 + l15;
            if (o < DEPN) {
                float p = e[nt] * inv;
                ps[row * 64 + o] = p;
                dout[DEPTH_OFF + ((size_t)bn * DEPN + o) * HW + pix] = p;
            } else fs[row * 64 + (o - DEPN)] = v[nt];     // o in 59..63 (nt==3 tail)
        }
        #pragma unroll
        for (int nt = 4; nt < 8; ++nt) {
            int o = nt * 16 + l15;
            if (o < NOUT) fs[row * 64 + (o - DEPN)] = acc[nt][reg] + bb[nt];
        }
    }
}

// ---------------- K2b: geometry + group-GEMM (16-depth chunks) ----------------
#define DQ2 16
__global__ __launch_bounds__(256) void k2b_geom(float* __restrict__ ws,
                                                float* __restrict__ dout) {
    __shared__ float sF[96][64];               // feats
    __shared__ float sP[DQ2][97];              // p tile, transposed, padded
    __shared__ unsigned short sv16[DQ2 * 96];  // voxel id or 0xFFFF
    __shared__ double sT[N_ * TDREC];
    __shared__ int sflag[DQ2];
    const int tid = threadIdx.x;
    const int bw = blockIdx.x;
    const int b = bw / FW, w = bw - b * FW;
    const int dbase = blockIdx.y * DQ2;
    const int nd = min(DQ2, DEPN - dbase);

    {   // stage F + P(transposed via coalesced float4) + transforms
        const float* fsrc = ws + WS_FS + (size_t)bw * (96 * 64);
        const float* psrc = ws + WS_PS + (size_t)bw * (96 * 64);
        for (int i = tid; i < 96 * 16; i += 256) {
            int j = i >> 4, c4 = (i & 15) * 4;
            *(float4*)&sF[j][c4] = *(const float4*)(fsrc + j * 64 + c4);
        }
        for (int i = tid; i < 96 * 4; i += 256) {       // was: 1536 stride-256B scalars
            int j = i >> 2, q = i & 3;
            const float4 p4 = *(const float4*)(psrc + j * 64 + dbase + 4 * q);
            sP[4 * q + 0][j] = p4.x; sP[4 * q + 1][j] = p4.y;
            sP[4 * q + 2][j] = p4.z; sP[4 * q + 3][j] = p4.w;
        }
        if (tid < N_ * TDREC) sT[tid] = ((const double*)ws)[b * (N_ * TDREC) + tid];
    }
    __syncthreads();

    {   // geometry: bit-exact validated f64 chain (R1-R5 ulp analysis)
        #pragma clang fp contract(off)
        const double xs = (w == 43) ? 703.0 : (double)w * (703.0 / 43.0);
        const double BXY = (double)(-51.2000007629394531f);  // f32 value of BX-DX/2
        for (int idx = tid; idx < nd * 96; idx += 256) {
            int dl = idx / 96, j = idx - dl * 96;
            int n = j >> 4, h = j & 15;
            const double* T = &sT[n * TDREC];
            const double ys = (double)(h * 17);
            const double u0 = xs - T[9];
            const double u1 = ys - T[10];
            const double u2 = (double)(dbase + dl + 1) - T[11];
            const double p0 = (T[0]*u0 + T[1]*u1) + T[2]*u2;
            const double p1 = (T[3]*u0 + T[4]*u1) + T[5]*u2;
            const double p2 = (T[6]*u0 + T[7]*u1) + T[8]*u2;
            const double q0 = p0 * p2, q1 = p1 * p2, q2 = p2;
            const double r0 = ((T[12]*q0 + T[13]*q1) + T[14]*q2) + T[21];
            const double r1 = ((T[15]*q0 + T[16]*q1) + T[17]*q2) + T[22];
            const double r2 = ((T[18]*q0 + T[19]*q1) + T[20]*q2) + T[23];
            const double g0 = (T[24]*r0 + T[25]*r1) + T[26]*r2;
            const double g1 = (T[27]*r0 + T[28]*r1) + T[29]*r2;
            const double g2 = (T[30]*r0 + T[31]*r1) + T[32]*r2;
            const double fx = floor((g0 - BXY) / 0.8);
            const double fy = floor((g1 - BXY) / 0.8);
            const bool keep = (fx >= 0.0) & (fx < 128.0) & (fy >= 0.0) & (fy < 128.0) &
                              (g2 >= -10.0) & (g2 < 10.0);
            sv16[idx] = keep ? (unsigned short)((int)fx * NX + (int)fy) : (unsigned short)0xFFFF;
        }
    }
    __syncthreads();

    // flags + mask dropped p's
    if (tid < nd) {
        int u = -1; bool mix = false;
        for (int j = 0; j < 96; ++j) {
            int v = sv16[tid * 96 + j];
            if (v != 0xFFFF) { if (u < 0) u = v; else if (v != u) mix = true; }
        }
        sflag[tid] = mix ? -2 : u;
        ((int*)(ws + WS_VOX))[bw * DEPN + dbase + tid] = mix ? -1 : u;
    }
    for (int idx = tid; idx < nd * 96; idx += 256) {
        if (sv16[idx] == 0xFFFF) {
            int dl = idx / 96, j = idx - dl * 96;
            sP[dl][j] = 0.0f;
        }
    }
    __syncthreads();

    // GEMM: C[d][c] = sum_j p[dl][j] * f[j][c]; thread = (dl, 4 channels)
    const int dl = tid >> 4, ci = tid & 15;
    if (dl < nd) {
        float a0 = 0.f, a1 = 0.f, a2 = 0.f, a3 = 0.f;
        for (int j = 0; j < 96; ++j) {
            const float p = sP[dl][j];
            const float4 f4 = *(const float4*)&sF[j][4 * ci];
            a0 = fmaf(p, f4.x, a0); a1 = fmaf(p, f4.y, a1);
            a2 = fmaf(p, f4.z, a2); a3 = fmaf(p, f4.w, a3);
        }
        float* cg = ws + WS_C + (size_t)bw * (DEPN * 64);
        float4 st = { a0, a1, a2, a3 };
        *(float4*)&cg[(dbase + dl) * 64 + 4 * ci] = st;
    }
    // rare per-point slow path for mixed groups
    for (int d2 = 0; d2 < nd; ++d2) {
        if (sflag[d2] == -2) {
            int c = tid & 63, g = tid >> 6;
            for (int jj = 0; jj < 24; ++jj) {
                int j = g * 24 + jj;
                int v = sv16[d2 * 96 + j];
                if (v != 0xFFFF)
                    atomicAdd(dout + (((size_t)(b * CT + c)) << 14) + v,
                              sP[d2][j] * sF[j][c]);
            }
        }
    }
}

// ---------------- K2c: per-(b,d) voxel reduction (depth now written by K1) ----------------
__global__ __launch_bounds__(256) void k2c_reduce(const float* __restrict__ ws,
                                                  float* __restrict__ dout) {
    __shared__ float acc[FW][64];
    __shared__ int tags[FW];
    __shared__ unsigned char slot[FW];
    __shared__ int wvox[FW];
    __shared__ int nsh;
    const int d = blockIdx.x, b = blockIdx.y;
    const int tid = threadIdx.x;
    if (tid < FW) wvox[tid] = ((const int*)(ws + WS_VOX))[(b * FW + tid) * DEPN + d];
    for (int i = tid; i < FW * 64; i += 256) (&acc[0][0])[i] = 0.0f;
    __syncthreads();
    if (tid < 64) {  // wave 0: dedup voxel ids into slots
        const int lane = tid;
        int v = (lane < FW) ? wvox[lane] : -1;
        int firstw = lane;
        for (int w2 = 0; w2 < FW; ++w2) {
            int vw = __shfl(v, w2, 64);
            if (v >= 0 && vw == v && w2 < firstw) firstw = w2;
        }
        unsigned long long leaders = __ballot(v >= 0 && firstw == lane);
        if (lane < FW) {
            if (v >= 0) {
                int s = __popcll(leaders & ((1ull << firstw) - 1ull));
                slot[lane] = (unsigned char)s;
                if (firstw == lane) tags[s] = v;
            } else slot[lane] = 255;
        }
        if (lane == 0) nsh = __popcll(leaders);
    }
    __syncthreads();
    const int c = tid & 63, g = tid >> 6;
    for (int w = g; w < FW; w += 4) {
        if (wvox[w] >= 0) {
            float v = ws[WS_C + ((size_t)(b * FW + w) * DEPN + d) * 64 + c];
            atomicAdd(&acc[slot[w]][c], v);
        }
    }
    __syncthreads();
    const int ns = nsh;
    for (int s = g; s < ns; s += 4)
        atomicAdd(dout + (((size_t)(b * CT + c)) << 14) + tags[s], acc[s][c]);
}

// ---------------- launcher ----------------
extern "C" void kernel_launch(void* const* d_in, const int* in_sizes, int n_in,
                              void* d_out, int out_size, void* d_ws, size_t ws_size,
                              hipStream_t stream) {
    const float* x      = (const float*)d_in[0];
    const float* rots   = (const float*)d_in[1];
    const float* trans  = (const float*)d_in[2];
    const float* intr   = (const float*)d_in[3];
    const float* prots  = (const float*)d_in[4];
    const float* ptrans = (const float*)d_in[5];
    const float* bda    = (const float*)d_in[6];
    const float* W      = (const float*)d_in[7];
    const float* bias   = (const float*)d_in[8];
    float* out = (float*)d_out;
    float* ws  = (float*)d_ws;

    hipMemsetAsync(d_out, 0, (size_t)BEV_ELEMS * sizeof(float), stream);
    k0_prep<<<128, 256, 0, stream>>>(rots, trans, intr, prots, ptrans, bda, W, ws);
    k1_gemm<<<dim3(HW / 64, B_ * N_), 256, 0, stream>>>(x, bias, ws, out);
    k2b_geom<<<dim3(B_ * FW, 4), 256, 0, stream>>>(ws, out);
    k2c_reduce<<<dim3(DEPN, B_), 256, 0, stream>>>(ws, out);
}

// Round 2
// 182.161 us; speedup vs baseline: 1.0417x; 1.0059x over previous
//
#include <hip/hip_runtime.h>
#include <math.h>

// ---------------- problem constants ----------------
#define CIN   512
#define NOUT  123      // DEPTH + CT
#define DEPN  59
#define CT    64
#define B_    4
#define N_    6
#define FH    16
#define FW    44
#define HW    704      // FH*FW
#define NPIX  (B_*N_*HW)          // 16896
#define NX    128
#define BEV_ELEMS (B_*CT*NX*NX)   // 4,194,304
#define DEPTH_OFF BEV_ELEMS

// ws layout (float offsets). Double region first (8B aligned at base).
#define TDREC   40
#define WS_WB   1920                       // bf16 weight [128 o][512 c]
#define WS_PS   (WS_WB + 32768)            // p-slab  [row = bw*96 + n*16+h][64] (cols 0..58)
#define WS_FS   (WS_PS + NPIX*64)          // f-slab  [row][64]
#define WS_C    (WS_FS + NPIX*64)          // group sums [bw][59][64]
#define WS_VOX  (WS_C + B_*FW*DEPN*64)     // int [bw][59]

typedef short bf16x8 __attribute__((ext_vector_type(8)));
typedef float f32x4  __attribute__((ext_vector_type(4)));

__device__ inline unsigned short f2bf(float f) {   // RNE f32->bf16
    unsigned u = __float_as_uint(f);
    return (unsigned short)((u + 0x7fffu + ((u >> 16) & 1u)) >> 16);
}

// ---------------- K0: bf16 weight build + per-(b,n) f64 transforms ----------------
__device__ inline void inv3d(const double* m, double* o) {
    #pragma clang fp contract(off)
    double c00 = m[4]*m[8] - m[5]*m[7];
    double c01 = m[5]*m[6] - m[3]*m[8];
    double c02 = m[3]*m[7] - m[4]*m[6];
    double det = m[0]*c00 + m[1]*c01 + m[2]*c02;
    o[0] = c00/det; o[1] = (m[2]*m[7]-m[1]*m[8])/det; o[2] = (m[1]*m[5]-m[2]*m[4])/det;
    o[3] = c01/det; o[4] = (m[0]*m[8]-m[2]*m[6])/det; o[5] = (m[2]*m[3]-m[0]*m[5])/det;
    o[6] = c02/det; o[7] = (m[1]*m[6]-m[0]*m[7])/det; o[8] = (m[0]*m[4]-m[1]*m[3])/det;
}
__device__ inline void mm3d(const double* a, const double* b, double* o) {
    #pragma clang fp contract(off)
    for (int i = 0; i < 3; ++i)
        for (int k = 0; k < 3; ++k)
            o[i*3+k] = (a[i*3+0]*b[0*3+k] + a[i*3+1]*b[1*3+k]) + a[i*3+2]*b[2*3+k];
}

__global__ void k0_prep(const float* __restrict__ rots, const float* __restrict__ trans,
                        const float* __restrict__ intr, const float* __restrict__ prots,
                        const float* __restrict__ ptrans, const float* __restrict__ bda,
                        const float* __restrict__ W, float* __restrict__ ws) {
    int tid = blockIdx.x * 256 + threadIdx.x;
    int stride = gridDim.x * 256;
    unsigned short* wb = (unsigned short*)(ws + WS_WB);
    for (int i = tid; i < 128 * CIN; i += stride) {
        int o = i >> 9, c = i & 511;
        wb[i] = (o < NOUT) ? f2bf(W[o * CIN + c]) : (unsigned short)0;
    }
    if (blockIdx.x == 0 && threadIdx.x < B_ * N_) {
        #pragma clang fp contract(off)
        int t = threadIdx.x;
        int b = t / N_;
        double* X = (double*)(ws) + t * TDREC;
        double PR[9], Kd[9], Rd[9], Bd[9];
        for (int i = 0; i < 9; ++i) PR[i] = (double)prots[t * 9 + i];
        for (int i = 0; i < 9; ++i) Kd[i] = (double)intr[t * 9 + i];
        for (int i = 0; i < 9; ++i) Rd[i] = (double)rots[t * 9 + i];
        for (int i = 0; i < 9; ++i) Bd[i] = (double)bda[b * 9 + i];
        double iPR[9]; inv3d(PR, iPR);
        for (int i = 0; i < 9; ++i) X[i] = iPR[i];
        for (int i = 0; i < 3; ++i) X[9 + i] = (double)ptrans[t * 3 + i];
        double iK[9];  inv3d(Kd, iK);
        double comb[9]; mm3d(Rd, iK, comb);
        for (int i = 0; i < 9; ++i) X[12 + i] = comb[i];
        for (int i = 0; i < 3; ++i) X[21 + i] = (double)trans[t * 3 + i];
        for (int i = 0; i < 9; ++i) X[24 + i] = Bd[i];
    }
}

// ---------------- K1: split-K bf16 MFMA GEMM + fused softmax epilogue ----------------
// v3: 512 threads / block. Wave-group 0 (waves 0-3) does K=0..255, group 1 does
// K=256..511, each with its own double-buffered LDS tiles (halves the serial
// latency chain AND doubles waves/SIMD). Partials merged via padded LDS reduce.
// Depth output now written COALESCED via LDS transpose (was 4B-stride scatter).
#define K1A   (64 * 72)                 // A tile shorts
#define K1T   (K1A + 128 * 72)          // shorts per (group,buf) tile = 13824
__global__ __launch_bounds__(512) void k1_gemm(const float* __restrict__ x,
                                               const float* __restrict__ bias,
                                               float* __restrict__ ws,
                                               float* __restrict__ dout) {
    __shared__ __align__(16) unsigned short smem[2][2][K1T];   // 110,592 B
    const int tid = threadIdx.x;
    const int grp = tid >> 8;             // K-half
    const int gtid = tid & 255;
    const int wave = gtid >> 6;           // wave within group (0..3)
    const int lane = tid & 63;
    const int l15 = lane & 15, quad = lane >> 4;
    const int bn = blockIdx.y;
    const int pixbase = blockIdx.x * 64;
    const float* xg = x + (size_t)bn * CIN * HW + pixbase;
    const unsigned short* wbg = (const unsigned short*)(ws + WS_WB);
    const int cpack = gtid >> 4;          // 0..15 (channel group of 4)
    const int pix4 = (gtid & 15) * 4;     // pixel group of 4
    const int wo  = gtid >> 3;            // weight-stage row (0..31)
    const int wsub = gtid & 7;            // weight-stage 16B sub-chunk
    const int ck0 = grp * 256;

    f32x4 acc[8] = {};
    float4 r0, r1, r2, r3;                // prefetched x tile (4c x 4pix)
    uint4  w4[4];                         // prefetched weight tile chunks

    {   // prologue: loads for this group's first K-step
        const float* src = xg + (size_t)(ck0 + 4 * cpack) * HW + pix4;
        r0 = *(const float4*)(src);
        r1 = *(const float4*)(src + HW);
        r2 = *(const float4*)(src + 2 * HW);
        r3 = *(const float4*)(src + 3 * HW);
        #pragma unroll
        for (int i = 0; i < 4; ++i)
            w4[i] = *(const uint4*)(wbg + (size_t)(wo + 32 * i) * CIN + ck0 + wsub * 8);
    }

    #pragma unroll
    for (int it = 0; it < 4; ++it) {
        const int buf = it & 1;
        unsigned short* sa = smem[grp][buf];            // [64][72]
        unsigned short* sb = smem[grp][buf] + K1A;      // [128][72]
        {   // store staged regs -> LDS (waits the prefetch vmcnt)
            const float* f0 = (const float*)&r0; const float* f1 = (const float*)&r1;
            const float* f2 = (const float*)&r2; const float* f3 = (const float*)&r3;
            #pragma unroll
            for (int i = 0; i < 4; ++i) {
                uint2 pk;
                pk.x = (unsigned)f2bf(f0[i]) | ((unsigned)f2bf(f1[i]) << 16);
                pk.y = (unsigned)f2bf(f2[i]) | ((unsigned)f2bf(f3[i]) << 16);
                *(uint2*)&sa[(pix4 + i) * 72 + 4 * cpack] = pk;
            }
            #pragma unroll
            for (int i = 0; i < 4; ++i)
                *(uint4*)&sb[(wo + 32 * i) * 72 + wsub * 8] = w4[i];
        }
        if (it < 3) {   // prefetch next K-step (overlaps MFMA phase below)
            const int ck = ck0 + (it + 1) * 64;
            const float* src = xg + (size_t)(ck + 4 * cpack) * HW + pix4;
            r0 = *(const float4*)(src);
            r1 = *(const float4*)(src + HW);
            r2 = *(const float4*)(src + 2 * HW);
            r3 = *(const float4*)(src + 3 * HW);
            #pragma unroll
            for (int i = 0; i < 4; ++i)
                w4[i] = *(const uint4*)(wbg + (size_t)(wo + 32 * i) * CIN + ck + wsub * 8);
        }
        __syncthreads();
        #pragma unroll
        for (int ks = 0; ks < 64; ks += 32) {
            const bf16x8 a = *(const bf16x8*)&sa[(wave * 16 + l15) * 72 + ks + quad * 8];
            #pragma unroll
            for (int nt = 0; nt < 8; ++nt) {
                const bf16x8 b = *(const bf16x8*)&sb[(nt * 16 + l15) * 72 + ks + quad * 8];
                acc[nt] = __builtin_amdgcn_mfma_f32_16x16x32_bf16(a, b, acc[nt], 0, 0, 0);
            }
        }
    }

    // ---- split-K reduce via LDS (tiles are dead; overlay). red[64][132] padded:
    // bank = (4*pix + o) & 31 -> quads land on distinct bank groups, conflict-free.
    __syncthreads();
    float* red = (float*)&smem[0][0][0];
    if (grp == 1) {
        #pragma unroll
        for (int nt = 0; nt < 8; ++nt)
            #pragma unroll
            for (int reg = 0; reg < 4; ++reg)
                red[(wave * 16 + quad * 4 + reg) * 132 + nt * 16 + l15] = acc[nt][reg];
    }
    __syncthreads();
    if (grp == 0) {
        #pragma unroll
        for (int nt = 0; nt < 8; ++nt)
            #pragma unroll
            for (int reg = 0; reg < 4; ++reg)
                acc[nt][reg] += red[(wave * 16 + quad * 4 + reg) * 132 + nt * 16 + l15];
    }
    __syncthreads();   // red dead; sred overlays same memory below

    // ---- epilogue (group 0 only): softmax + split store + p into LDS transpose.
    // sred[64][65]: bank = (pix + o) & 31 -> 2-way on both phases (free).
    float* sred = (float*)&smem[0][0][0];
    const int b = bn / N_, n = bn - b * N_;
    if (grp == 0) {
        float bb[8];
        #pragma unroll
        for (int nt = 0; nt < 8; ++nt) {
            int o = nt * 16 + l15;
            bb[nt] = (o < NOUT) ? bias[o] : 0.0f;
        }
        float* ps = ws + WS_PS;
        float* fs = ws + WS_FS;
        #pragma unroll
        for (int reg = 0; reg < 4; ++reg) {
            int pixl = wave * 16 + quad * 4 + reg;
            int pix = pixbase + pixl;
            int h = pix / FW, w = pix - h * FW;
            size_t row = (size_t)(b * FW + w) * 96 + n * FH + h;
            float v[4]; float m = -INFINITY;
            #pragma unroll
            for (int nt = 0; nt < 4; ++nt) {
                v[nt] = acc[nt][reg] + bb[nt];
                if (nt * 16 + l15 < DEPN) m = fmaxf(m, v[nt]);
            }
            #pragma unroll
            for (int msk = 8; msk >= 1; msk >>= 1) m = fmaxf(m, __shfl_xor(m, msk, 64));
            float e[4], s = 0.0f;
            #pragma unroll
            for (int nt = 0; nt < 4; ++nt) {
                e[nt] = (nt * 16 + l15 < DEPN) ? expf(v[nt] - m) : 0.0f;
                s += e[nt];
            }
            #pragma unroll
            for (int msk = 8; msk >= 1; msk >>= 1) s += __shfl_xor(s, msk, 64);
            const float inv = 1.0f / s;
            #pragma unroll
            for (int nt = 0; nt < 4; ++nt) {
                int o = nt * 16 + l15;
                if (o < DEPN) {
                    float p = e[nt] * inv;
                    ps[row * 64 + o] = p;
                    sred[pixl * 65 + o] = p;
                } else fs[row * 64 + (o - DEPN)] = v[nt];   // o in 59..63 (nt==3 tail)
            }
            #pragma unroll
            for (int nt = 4; nt < 8; ++nt) {
                int o = nt * 16 + l15;
                if (o < NOUT) fs[row * 64 + (o - DEPN)] = acc[nt][reg] + bb[nt];
            }
        }
    }
    __syncthreads();
    // ---- coalesced depth write: 8 waves x o-rows, 256B contiguous per store
    const int wv8 = tid >> 6;
    for (int o = wv8; o < DEPN; o += 8)
        dout[DEPTH_OFF + ((size_t)bn * DEPN + o) * HW + pixbase + lane] = sred[lane * 65 + o];
}

// ---------------- K2b: geometry + group-GEMM (16-depth chunks) ----------------
#define DQ2 16
__global__ __launch_bounds__(256) void k2b_geom(float* __restrict__ ws,
                                                float* __restrict__ dout) {
    __shared__ float sF[96][64];               // feats
    __shared__ float sP[DQ2][97];              // p tile, transposed, padded
    __shared__ unsigned short sv16[DQ2 * 96];  // voxel id or 0xFFFF
    __shared__ double sT[N_ * TDREC];
    __shared__ int sflag[DQ2];
    const int tid = threadIdx.x;
    const int bw = blockIdx.x;
    const int b = bw / FW, w = bw - b * FW;
    const int dbase = blockIdx.y * DQ2;
    const int nd = min(DQ2, DEPN - dbase);

    {   // stage F + P(transposed via coalesced float4) + transforms
        const float* fsrc = ws + WS_FS + (size_t)bw * (96 * 64);
        const float* psrc = ws + WS_PS + (size_t)bw * (96 * 64);
        for (int i = tid; i < 96 * 16; i += 256) {
            int j = i >> 4, c4 = (i & 15) * 4;
            *(float4*)&sF[j][c4] = *(const float4*)(fsrc + j * 64 + c4);
        }
        for (int i = tid; i < 96 * 4; i += 256) {
            int j = i >> 2, q = i & 3;
            const float4 p4 = *(const float4*)(psrc + j * 64 + dbase + 4 * q);
            sP[4 * q + 0][j] = p4.x; sP[4 * q + 1][j] = p4.y;
            sP[4 * q + 2][j] = p4.z; sP[4 * q + 3][j] = p4.w;
        }
        if (tid < N_ * TDREC) sT[tid] = ((const double*)ws)[b * (N_ * TDREC) + tid];
    }
    __syncthreads();

    {   // geometry: bit-exact validated f64 chain (R1-R5 ulp analysis)
        #pragma clang fp contract(off)
        const double xs = (w == 43) ? 703.0 : (double)w * (703.0 / 43.0);
        const double BXY = (double)(-51.2000007629394531f);  // f32 value of BX-DX/2
        for (int idx = tid; idx < nd * 96; idx += 256) {
            int dl = idx / 96, j = idx - dl * 96;
            int n = j >> 4, h = j & 15;
            const double* T = &sT[n * TDREC];
            const double ys = (double)(h * 17);
            const double u0 = xs - T[9];
            const double u1 = ys - T[10];
            const double u2 = (double)(dbase + dl + 1) - T[11];
            const double p0 = (T[0]*u0 + T[1]*u1) + T[2]*u2;
            const double p1 = (T[3]*u0 + T[4]*u1) + T[5]*u2;
            const double p2 = (T[6]*u0 + T[7]*u1) + T[8]*u2;
            const double q0 = p0 * p2, q1 = p1 * p2, q2 = p2;
            const double r0 = ((T[12]*q0 + T[13]*q1) + T[14]*q2) + T[21];
            const double r1 = ((T[15]*q0 + T[16]*q1) + T[17]*q2) + T[22];
            const double r2 = ((T[18]*q0 + T[19]*q1) + T[20]*q2) + T[23];
            const double g0 = (T[24]*r0 + T[25]*r1) + T[26]*r2;
            const double g1 = (T[27]*r0 + T[28]*r1) + T[29]*r2;
            const double g2 = (T[30]*r0 + T[31]*r1) + T[32]*r2;
            const double fx = floor((g0 - BXY) / 0.8);
            const double fy = floor((g1 - BXY) / 0.8);
            const bool keep = (fx >= 0.0) & (fx < 128.0) & (fy >= 0.0) & (fy < 128.0) &
                              (g2 >= -10.0) & (g2 < 10.0);
            sv16[idx] = keep ? (unsigned short)((int)fx * NX + (int)fy) : (unsigned short)0xFFFF;
        }
    }
    __syncthreads();

    // flags + mask dropped p's
    if (tid < nd) {
        int u = -1; bool mix = false;
        for (int j = 0; j < 96; ++j) {
            int v = sv16[tid * 96 + j];
            if (v != 0xFFFF) { if (u < 0) u = v; else if (v != u) mix = true; }
        }
        sflag[tid] = mix ? -2 : u;
        ((int*)(ws + WS_VOX))[bw * DEPN + dbase + tid] = mix ? -1 : u;
    }
    for (int idx = tid; idx < nd * 96; idx += 256) {
        if (sv16[idx] == 0xFFFF) {
            int dl = idx / 96, j = idx - dl * 96;
            sP[dl][j] = 0.0f;
        }
    }
    __syncthreads();

    // GEMM: C[d][c] = sum_j p[dl][j] * f[j][c]; thread = (dl, 4 channels)
    const int dl = tid >> 4, ci = tid & 15;
    if (dl < nd) {
        float a0 = 0.f, a1 = 0.f, a2 = 0.f, a3 = 0.f;
        for (int j = 0; j < 96; ++j) {
            const float p = sP[dl][j];
            const float4 f4 = *(const float4*)&sF[j][4 * ci];
            a0 = fmaf(p, f4.x, a0); a1 = fmaf(p, f4.y, a1);
            a2 = fmaf(p, f4.z, a2); a3 = fmaf(p, f4.w, a3);
        }
        float* cg = ws + WS_C + (size_t)bw * (DEPN * 64);
        float4 st = { a0, a1, a2, a3 };
        *(float4*)&cg[(dbase + dl) * 64 + 4 * ci] = st;
    }
    // rare per-point slow path for mixed groups
    for (int d2 = 0; d2 < nd; ++d2) {
        if (sflag[d2] == -2) {
            int c = tid & 63, g = tid >> 6;
            for (int jj = 0; jj < 24; ++jj) {
                int j = g * 24 + jj;
                int v = sv16[d2 * 96 + j];
                if (v != 0xFFFF)
                    atomicAdd(dout + (((size_t)(b * CT + c)) << 14) + v,
                              sP[d2][j] * sF[j][c]);
            }
        }
    }
}

// ---------------- K2c: per-(b,d) voxel reduction (depth written by K1) ----------------
__global__ __launch_bounds__(256) void k2c_reduce(const float* __restrict__ ws,
                                                  float* __restrict__ dout) {
    __shared__ float acc[FW][64];
    __shared__ int tags[FW];
    __shared__ unsigned char slot[FW];
    __shared__ int wvox[FW];
    __shared__ int nsh;
    const int d = blockIdx.x, b = blockIdx.y;
    const int tid = threadIdx.x;
    if (tid < FW) wvox[tid] = ((const int*)(ws + WS_VOX))[(b * FW + tid) * DEPN + d];
    for (int i = tid; i < FW * 64; i += 256) (&acc[0][0])[i] = 0.0f;
    __syncthreads();
    if (tid < 64) {  // wave 0: dedup voxel ids into slots
        const int lane = tid;
        int v = (lane < FW) ? wvox[lane] : -1;
        int firstw = lane;
        for (int w2 = 0; w2 < FW; ++w2) {
            int vw = __shfl(v, w2, 64);
            if (v >= 0 && vw == v && w2 < firstw) firstw = w2;
        }
        unsigned long long leaders = __ballot(v >= 0 && firstw == lane);
        if (lane < FW) {
            if (v >= 0) {
                int s = __popcll(leaders & ((1ull << firstw) - 1ull));
                slot[lane] = (unsigned char)s;
                if (firstw == lane) tags[s] = v;
            } else slot[lane] = 255;
        }
        if (lane == 0) nsh = __popcll(leaders);
    }
    __syncthreads();
    const int c = tid & 63, g = tid >> 6;
    for (int w = g; w < FW; w += 4) {
        if (wvox[w] >= 0) {
            float v = ws[WS_C + ((size_t)(b * FW + w) * DEPN + d) * 64 + c];
            atomicAdd(&acc[slot[w]][c], v);
        }
    }
    __syncthreads();
    const int ns = nsh;
    for (int s = g; s < ns; s += 4)
        atomicAdd(dout + (((size_t)(b * CT + c)) << 14) + tags[s], acc[s][c]);
}

// ---------------- launcher ----------------
extern "C" void kernel_launch(void* const* d_in, const int* in_sizes, int n_in,
                              void* d_out, int out_size, void* d_ws, size_t ws_size,
                              hipStream_t stream) {
    const float* x      = (const float*)d_in[0];
    const float* rots   = (const float*)d_in[1];
    const float* trans  = (const float*)d_in[2];
    const float* intr   = (const float*)d_in[3];
    const float* prots  = (const float*)d_in[4];
    const float* ptrans = (const float*)d_in[5];
    const float* bda    = (const float*)d_in[6];
    const float* W      = (const float*)d_in[7];
    const float* bias   = (const float*)d_in[8];
    float* out = (float*)d_out;
    float* ws  = (float*)d_ws;

    hipMemsetAsync(d_out, 0, (size_t)BEV_ELEMS * sizeof(float), stream);
    k0_prep<<<128, 256, 0, stream>>>(rots, trans, intr, prots, ptrans, bda, W, ws);
    k1_gemm<<<dim3(HW / 64, B_ * N_), 512, 0, stream>>>(x, bias, ws, out);
    k2b_geom<<<dim3(B_ * FW, 4), 256, 0, stream>>>(ws, out);
    k2c_reduce<<<dim3(DEPN, B_), 256, 0, stream>>>(ws, out);
}

// Round 3
// 168.422 us; speedup vs baseline: 1.1267x; 1.0816x over previous
//
#include <hip/hip_runtime.h>
#include <math.h>

// ---------------- problem constants ----------------
#define CIN   512
#define NOUT  123      // DEPTH + CT
#define DEPN  59
#define CT    64
#define B_    4
#define N_    6
#define FH    16
#define FW    44
#define HW    704      // FH*FW
#define NPIX  (B_*N_*HW)          // 16896
#define NX    128
#define BEV_ELEMS (B_*CT*NX*NX)   // 4,194,304
#define DEPTH_OFF BEV_ELEMS

// ws layout (float offsets). Double region first (8B aligned at base).
#define TDREC   40
#define WS_WB   1920                       // bf16 weight [128 o][512 c]
#define WS_PS   (WS_WB + 32768)            // p-slab  [row = bw*96 + n*16+h][64] (cols 0..58)
#define WS_FS   (WS_PS + NPIX*64)          // f-slab  [row][64]

typedef short bf16x8 __attribute__((ext_vector_type(8)));
typedef float f32x4  __attribute__((ext_vector_type(4)));

__device__ inline unsigned short f2bf(float f) {   // RNE f32->bf16
    unsigned u = __float_as_uint(f);
    return (unsigned short)((u + 0x7fffu + ((u >> 16) & 1u)) >> 16);
}

// ---------------- K0: dout zero + bf16 weight build + per-(b,n) f64 transforms ----------------
__device__ inline void inv3d(const double* m, double* o) {
    #pragma clang fp contract(off)
    double c00 = m[4]*m[8] - m[5]*m[7];
    double c01 = m[5]*m[6] - m[3]*m[8];
    double c02 = m[3]*m[7] - m[4]*m[6];
    double det = m[0]*c00 + m[1]*c01 + m[2]*c02;
    o[0] = c00/det; o[1] = (m[2]*m[7]-m[1]*m[8])/det; o[2] = (m[1]*m[5]-m[2]*m[4])/det;
    o[3] = c01/det; o[4] = (m[0]*m[8]-m[2]*m[6])/det; o[5] = (m[2]*m[3]-m[0]*m[5])/det;
    o[6] = c02/det; o[7] = (m[1]*m[6]-m[0]*m[7])/det; o[8] = (m[0]*m[4]-m[1]*m[3])/det;
}
__device__ inline void mm3d(const double* a, const double* b, double* o) {
    #pragma clang fp contract(off)
    for (int i = 0; i < 3; ++i)
        for (int k = 0; k < 3; ++k)
            o[i*3+k] = (a[i*3+0]*b[0*3+k] + a[i*3+1]*b[1*3+k]) + a[i*3+2]*b[2*3+k];
}

__global__ void k0_prep(const float* __restrict__ rots, const float* __restrict__ trans,
                        const float* __restrict__ intr, const float* __restrict__ prots,
                        const float* __restrict__ ptrans, const float* __restrict__ bda,
                        const float* __restrict__ W, float* __restrict__ ws,
                        float* __restrict__ dout) {
    int tid = blockIdx.x * 256 + threadIdx.x;
    int stride = gridDim.x * 256;
    // zero the BEV region of dout (depth region fully overwritten by k1)
    float4 z = {0.f, 0.f, 0.f, 0.f};
    for (int i = tid; i < BEV_ELEMS / 4; i += stride)
        *(float4*)(dout + 4 * (size_t)i) = z;
    unsigned short* wb = (unsigned short*)(ws + WS_WB);
    for (int i = tid; i < 128 * CIN; i += stride) {
        int o = i >> 9, c = i & 511;
        wb[i] = (o < NOUT) ? f2bf(W[o * CIN + c]) : (unsigned short)0;
    }
    if (blockIdx.x == 0 && threadIdx.x < B_ * N_) {
        #pragma clang fp contract(off)
        int t = threadIdx.x;
        int b = t / N_;
        double* X = (double*)(ws) + t * TDREC;
        double PR[9], Kd[9], Rd[9], Bd[9];
        for (int i = 0; i < 9; ++i) PR[i] = (double)prots[t * 9 + i];
        for (int i = 0; i < 9; ++i) Kd[i] = (double)intr[t * 9 + i];
        for (int i = 0; i < 9; ++i) Rd[i] = (double)rots[t * 9 + i];
        for (int i = 0; i < 9; ++i) Bd[i] = (double)bda[b * 9 + i];
        double iPR[9]; inv3d(PR, iPR);
        for (int i = 0; i < 9; ++i) X[i] = iPR[i];
        for (int i = 0; i < 3; ++i) X[9 + i] = (double)ptrans[t * 3 + i];
        double iK[9];  inv3d(Kd, iK);
        double comb[9]; mm3d(Rd, iK, comb);
        for (int i = 0; i < 9; ++i) X[12 + i] = comb[i];
        for (int i = 0; i < 3; ++i) X[21 + i] = (double)trans[t * 3 + i];
        for (int i = 0; i < 9; ++i) X[24 + i] = Bd[i];
    }
}

// ---------------- K1: split-K bf16 MFMA GEMM + fused softmax epilogue ----------------
// 512 threads / block. Wave-group 0 (waves 0-3) does K=0..255, group 1 does
// K=256..511, each with its own double-buffered LDS tiles. Partials merged via
// padded LDS reduce. Depth output written coalesced via LDS transpose.
#define K1A   (64 * 72)                 // A tile shorts
#define K1T   (K1A + 128 * 72)          // shorts per (group,buf) tile = 13824
__global__ __launch_bounds__(512) void k1_gemm(const float* __restrict__ x,
                                               const float* __restrict__ bias,
                                               float* __restrict__ ws,
                                               float* __restrict__ dout) {
    __shared__ __align__(16) unsigned short smem[2][2][K1T];   // 110,592 B
    const int tid = threadIdx.x;
    const int grp = tid >> 8;             // K-half
    const int gtid = tid & 255;
    const int wave = gtid >> 6;           // wave within group (0..3)
    const int lane = tid & 63;
    const int l15 = lane & 15, quad = lane >> 4;
    const int bn = blockIdx.y;
    const int pixbase = blockIdx.x * 64;
    const float* xg = x + (size_t)bn * CIN * HW + pixbase;
    const unsigned short* wbg = (const unsigned short*)(ws + WS_WB);
    const int cpack = gtid >> 4;          // 0..15 (channel group of 4)
    const int pix4 = (gtid & 15) * 4;     // pixel group of 4
    const int wo  = gtid >> 3;            // weight-stage row (0..31)
    const int wsub = gtid & 7;            // weight-stage 16B sub-chunk
    const int ck0 = grp * 256;

    f32x4 acc[8] = {};
    float4 r0, r1, r2, r3;                // prefetched x tile (4c x 4pix)
    uint4  w4[4];                         // prefetched weight tile chunks

    {   // prologue: loads for this group's first K-step
        const float* src = xg + (size_t)(ck0 + 4 * cpack) * HW + pix4;
        r0 = *(const float4*)(src);
        r1 = *(const float4*)(src + HW);
        r2 = *(const float4*)(src + 2 * HW);
        r3 = *(const float4*)(src + 3 * HW);
        #pragma unroll
        for (int i = 0; i < 4; ++i)
            w4[i] = *(const uint4*)(wbg + (size_t)(wo + 32 * i) * CIN + ck0 + wsub * 8);
    }

    #pragma unroll
    for (int it = 0; it < 4; ++it) {
        const int buf = it & 1;
        unsigned short* sa = smem[grp][buf];            // [64][72]
        unsigned short* sb = smem[grp][buf] + K1A;      // [128][72]
        {   // store staged regs -> LDS (waits the prefetch vmcnt)
            const float* f0 = (const float*)&r0; const float* f1 = (const float*)&r1;
            const float* f2 = (const float*)&r2; const float* f3 = (const float*)&r3;
            #pragma unroll
            for (int i = 0; i < 4; ++i) {
                uint2 pk;
                pk.x = (unsigned)f2bf(f0[i]) | ((unsigned)f2bf(f1[i]) << 16);
                pk.y = (unsigned)f2bf(f2[i]) | ((unsigned)f2bf(f3[i]) << 16);
                *(uint2*)&sa[(pix4 + i) * 72 + 4 * cpack] = pk;
            }
            #pragma unroll
            for (int i = 0; i < 4; ++i)
                *(uint4*)&sb[(wo + 32 * i) * 72 + wsub * 8] = w4[i];
        }
        if (it < 3) {   // prefetch next K-step (overlaps MFMA phase below)
            const int ck = ck0 + (it + 1) * 64;
            const float* src = xg + (size_t)(ck + 4 * cpack) * HW + pix4;
            r0 = *(const float4*)(src);
            r1 = *(const float4*)(src + HW);
            r2 = *(const float4*)(src + 2 * HW);
            r3 = *(const float4*)(src + 3 * HW);
            #pragma unroll
            for (int i = 0; i < 4; ++i)
                w4[i] = *(const uint4*)(wbg + (size_t)(wo + 32 * i) * CIN + ck + wsub * 8);
        }
        __syncthreads();
        #pragma unroll
        for (int ks = 0; ks < 64; ks += 32) {
            const bf16x8 a = *(const bf16x8*)&sa[(wave * 16 + l15) * 72 + ks + quad * 8];
            #pragma unroll
            for (int nt = 0; nt < 8; ++nt) {
                const bf16x8 b = *(const bf16x8*)&sb[(nt * 16 + l15) * 72 + ks + quad * 8];
                acc[nt] = __builtin_amdgcn_mfma_f32_16x16x32_bf16(a, b, acc[nt], 0, 0, 0);
            }
        }
    }

    // ---- split-K reduce via LDS (tiles are dead; overlay). red[64][132] padded.
    __syncthreads();
    float* red = (float*)&smem[0][0][0];
    if (grp == 1) {
        #pragma unroll
        for (int nt = 0; nt < 8; ++nt)
            #pragma unroll
            for (int reg = 0; reg < 4; ++reg)
                red[(wave * 16 + quad * 4 + reg) * 132 + nt * 16 + l15] = acc[nt][reg];
    }
    __syncthreads();
    if (grp == 0) {
        #pragma unroll
        for (int nt = 0; nt < 8; ++nt)
            #pragma unroll
            for (int reg = 0; reg < 4; ++reg)
                acc[nt][reg] += red[(wave * 16 + quad * 4 + reg) * 132 + nt * 16 + l15];
    }
    __syncthreads();   // red dead; sred overlays same memory below

    // ---- epilogue (group 0 only): softmax + split store + p into LDS transpose.
    float* sred = (float*)&smem[0][0][0];
    const int b = bn / N_, n = bn - b * N_;
    if (grp == 0) {
        float bb[8];
        #pragma unroll
        for (int nt = 0; nt < 8; ++nt) {
            int o = nt * 16 + l15;
            bb[nt] = (o < NOUT) ? bias[o] : 0.0f;
        }
        float* ps = ws + WS_PS;
        float* fs = ws + WS_FS;
        #pragma unroll
        for (int reg = 0; reg < 4; ++reg) {
            int pixl = wave * 16 + quad * 4 + reg;
            int pix = pixbase + pixl;
            int h = pix / FW, w = pix - h * FW;
            size_t row = (size_t)(b * FW + w) * 96 + n * FH + h;
            float v[4]; float m = -INFINITY;
            #pragma unroll
            for (int nt = 0; nt < 4; ++nt) {
                v[nt] = acc[nt][reg] + bb[nt];
                if (nt * 16 + l15 < DEPN) m = fmaxf(m, v[nt]);
            }
            #pragma unroll
            for (int msk = 8; msk >= 1; msk >>= 1) m = fmaxf(m, __shfl_xor(m, msk, 64));
            float e[4], s = 0.0f;
            #pragma unroll
            for (int nt = 0; nt < 4; ++nt) {
                e[nt] = (nt * 16 + l15 < DEPN) ? expf(v[nt] - m) : 0.0f;
                s += e[nt];
            }
            #pragma unroll
            for (int msk = 8; msk >= 1; msk >>= 1) s += __shfl_xor(s, msk, 64);
            const float inv = 1.0f / s;
            #pragma unroll
            for (int nt = 0; nt < 4; ++nt) {
                int o = nt * 16 + l15;
                if (o < DEPN) {
                    float p = e[nt] * inv;
                    ps[row * 64 + o] = p;
                    sred[pixl * 65 + o] = p;
                } else fs[row * 64 + (o - DEPN)] = v[nt];   // o in 59..63 (nt==3 tail)
            }
            #pragma unroll
            for (int nt = 4; nt < 8; ++nt) {
                int o = nt * 16 + l15;
                if (o < NOUT) fs[row * 64 + (o - DEPN)] = acc[nt][reg] + bb[nt];
            }
        }
    }
    __syncthreads();
    // ---- coalesced depth write: 8 waves x o-rows, 256B contiguous per store
    const int wv8 = tid >> 6;
    for (int o = wv8; o < DEPN; o += 8)
        dout[DEPTH_OFF + ((size_t)bn * DEPN + o) * HW + pixbase + lane] = sred[lane * 65 + o];
}

// ---------------- K2b: geometry + group-GEMM + DIRECT BEV atomics ----------------
// v4: group sums go straight to dout via atomicAdd (was: WS_C slab + k2c kernel).
#define DQ2 16
__global__ __launch_bounds__(256) void k2b_geom(float* __restrict__ ws,
                                                float* __restrict__ dout) {
    __shared__ float sF[96][64];               // feats
    __shared__ float sP[DQ2][97];              // p tile, transposed, padded
    __shared__ unsigned short sv16[DQ2 * 96];  // voxel id or 0xFFFF
    __shared__ double sT[N_ * TDREC];
    __shared__ int sflag[DQ2];
    const int tid = threadIdx.x;
    const int bw = blockIdx.x;
    const int b = bw / FW, w = bw - b * FW;
    const int dbase = blockIdx.y * DQ2;
    const int nd = min(DQ2, DEPN - dbase);

    {   // stage F + P(transposed via coalesced float4) + transforms
        const float* fsrc = ws + WS_FS + (size_t)bw * (96 * 64);
        const float* psrc = ws + WS_PS + (size_t)bw * (96 * 64);
        for (int i = tid; i < 96 * 16; i += 256) {
            int j = i >> 4, c4 = (i & 15) * 4;
            *(float4*)&sF[j][c4] = *(const float4*)(fsrc + j * 64 + c4);
        }
        for (int i = tid; i < 96 * 4; i += 256) {
            int j = i >> 2, q = i & 3;
            const float4 p4 = *(const float4*)(psrc + j * 64 + dbase + 4 * q);
            sP[4 * q + 0][j] = p4.x; sP[4 * q + 1][j] = p4.y;
            sP[4 * q + 2][j] = p4.z; sP[4 * q + 3][j] = p4.w;
        }
        if (tid < N_ * TDREC) sT[tid] = ((const double*)ws)[b * (N_ * TDREC) + tid];
    }
    __syncthreads();

    {   // geometry: bit-exact validated f64 chain (R1-R5 ulp analysis)
        #pragma clang fp contract(off)
        const double xs = (w == 43) ? 703.0 : (double)w * (703.0 / 43.0);
        const double BXY = (double)(-51.2000007629394531f);  // f32 value of BX-DX/2
        for (int idx = tid; idx < nd * 96; idx += 256) {
            int dl = idx / 96, j = idx - dl * 96;
            int n = j >> 4, h = j & 15;
            const double* T = &sT[n * TDREC];
            const double ys = (double)(h * 17);
            const double u0 = xs - T[9];
            const double u1 = ys - T[10];
            const double u2 = (double)(dbase + dl + 1) - T[11];
            const double p0 = (T[0]*u0 + T[1]*u1) + T[2]*u2;
            const double p1 = (T[3]*u0 + T[4]*u1) + T[5]*u2;
            const double p2 = (T[6]*u0 + T[7]*u1) + T[8]*u2;
            const double q0 = p0 * p2, q1 = p1 * p2, q2 = p2;
            const double r0 = ((T[12]*q0 + T[13]*q1) + T[14]*q2) + T[21];
            const double r1 = ((T[15]*q0 + T[16]*q1) + T[17]*q2) + T[22];
            const double r2 = ((T[18]*q0 + T[19]*q1) + T[20]*q2) + T[23];
            const double g0 = (T[24]*r0 + T[25]*r1) + T[26]*r2;
            const double g1 = (T[27]*r0 + T[28]*r1) + T[29]*r2;
            const double g2 = (T[30]*r0 + T[31]*r1) + T[32]*r2;
            const double fx = floor((g0 - BXY) / 0.8);
            const double fy = floor((g1 - BXY) / 0.8);
            const bool keep = (fx >= 0.0) & (fx < 128.0) & (fy >= 0.0) & (fy < 128.0) &
                              (g2 >= -10.0) & (g2 < 10.0);
            sv16[idx] = keep ? (unsigned short)((int)fx * NX + (int)fy) : (unsigned short)0xFFFF;
        }
    }
    __syncthreads();

    // flags + mask dropped p's
    if (tid < nd) {
        int u = -1; bool mix = false;
        for (int j = 0; j < 96; ++j) {
            int v = sv16[tid * 96 + j];
            if (v != 0xFFFF) { if (u < 0) u = v; else if (v != u) mix = true; }
        }
        sflag[tid] = mix ? -2 : u;
    }
    for (int idx = tid; idx < nd * 96; idx += 256) {
        if (sv16[idx] == 0xFFFF) {
            int dl = idx / 96, j = idx - dl * 96;
            sP[dl][j] = 0.0f;
        }
    }
    __syncthreads();

    // GEMM: C[d][c] = sum_j p[dl][j] * f[j][c]; thread = (dl, 4 channels).
    // Uniform-voxel groups (the only kind in this data) atomicAdd directly.
    const int dl = tid >> 4, ci = tid & 15;
    if (dl < nd && sflag[dl] >= 0) {
        float a0 = 0.f, a1 = 0.f, a2 = 0.f, a3 = 0.f;
        for (int j = 0; j < 96; ++j) {
            const float p = sP[dl][j];
            const float4 f4 = *(const float4*)&sF[j][4 * ci];
            a0 = fmaf(p, f4.x, a0); a1 = fmaf(p, f4.y, a1);
            a2 = fmaf(p, f4.z, a2); a3 = fmaf(p, f4.w, a3);
        }
        float* dst = dout + (((size_t)(b * CT + 4 * ci)) << 14) + sflag[dl];
        atomicAdd(dst,                 a0);
        atomicAdd(dst + (1 << 14),     a1);
        atomicAdd(dst + (2 << 14),     a2);
        atomicAdd(dst + (3 << 14),     a3);
    }
    // rare per-point slow path for mixed groups
    for (int d2 = 0; d2 < nd; ++d2) {
        if (sflag[d2] == -2) {
            int c = tid & 63, g = tid >> 6;
            for (int jj = 0; jj < 24; ++jj) {
                int j = g * 24 + jj;
                int v = sv16[d2 * 96 + j];
                if (v != 0xFFFF)
                    atomicAdd(dout + (((size_t)(b * CT + c)) << 14) + v,
                              sP[d2][j] * sF[j][c]);
            }
        }
    }
}

// ---------------- launcher ----------------
extern "C" void kernel_launch(void* const* d_in, const int* in_sizes, int n_in,
                              void* d_out, int out_size, void* d_ws, size_t ws_size,
                              hipStream_t stream) {
    const float* x      = (const float*)d_in[0];
    const float* rots   = (const float*)d_in[1];
    const float* trans  = (const float*)d_in[2];
    const float* intr   = (const float*)d_in[3];
    const float* prots  = (const float*)d_in[4];
    const float* ptrans = (const float*)d_in[5];
    const float* bda    = (const float*)d_in[6];
    const float* W      = (const float*)d_in[7];
    const float* bias   = (const float*)d_in[8];
    float* out = (float*)d_out;
    float* ws  = (float*)d_ws;

    k0_prep<<<512, 256, 0, stream>>>(rots, trans, intr, prots, ptrans, bda, W, ws, out);
    k1_gemm<<<dim3(HW / 64, B_ * N_), 512, 0, stream>>>(x, bias, ws, out);
    k2b_geom<<<dim3(B_ * FW, 4), 256, 0, stream>>>(ws, out);
}

// Round 4
// 161.061 us; speedup vs baseline: 1.1782x; 1.0457x over previous
//
#include <hip/hip_runtime.h>
#include <math.h>

// ---------------- problem constants ----------------
#define CIN   512
#define NOUT  123      // DEPTH + CT
#define DEPN  59
#define CT    64
#define B_    4
#define N_    6
#define FH    16
#define FW    44
#define HW    704      // FH*FW
#define NPIX  (B_*N_*HW)          // 16896
#define NX    128
#define BEV_ELEMS (B_*CT*NX*NX)   // 4,194,304
#define DEPTH_OFF BEV_ELEMS

// ws layout (float offsets). Double region first (8B aligned at base).
#define TDREC   40
#define WS_WB   1920                       // bf16 weight [128 o][512 c]
#define WS_PS   (WS_WB + 32768)            // p-slab  [row = bw*96 + n*16+h][64] (cols 0..58)
#define WS_FS   (WS_PS + NPIX*64)          // f-slab  [row][64]
#define WS_GC   (WS_FS + NPIX*64)          // f64 quad coeffs [bw][96 j][9]

typedef short bf16x8 __attribute__((ext_vector_type(8)));
typedef float f32x4  __attribute__((ext_vector_type(4)));

__device__ inline unsigned short f2bf(float f) {   // RNE f32->bf16
    unsigned u = __float_as_uint(f);
    return (unsigned short)((u + 0x7fffu + ((u >> 16) & 1u)) >> 16);
}

// ---------------- K0: dout zero + bf16 weight build + per-(b,n) f64 transforms ----------------
__device__ inline void inv3d(const double* m, double* o) {
    #pragma clang fp contract(off)
    double c00 = m[4]*m[8] - m[5]*m[7];
    double c01 = m[5]*m[6] - m[3]*m[8];
    double c02 = m[3]*m[7] - m[4]*m[6];
    double det = m[0]*c00 + m[1]*c01 + m[2]*c02;
    o[0] = c00/det; o[1] = (m[2]*m[7]-m[1]*m[8])/det; o[2] = (m[1]*m[5]-m[2]*m[4])/det;
    o[3] = c01/det; o[4] = (m[0]*m[8]-m[2]*m[6])/det; o[5] = (m[2]*m[3]-m[0]*m[5])/det;
    o[6] = c02/det; o[7] = (m[1]*m[6]-m[0]*m[7])/det; o[8] = (m[0]*m[4]-m[1]*m[3])/det;
}
__device__ inline void mm3d(const double* a, const double* b, double* o) {
    #pragma clang fp contract(off)
    for (int i = 0; i < 3; ++i)
        for (int k = 0; k < 3; ++k)
            o[i*3+k] = (a[i*3+0]*b[0*3+k] + a[i*3+1]*b[1*3+k]) + a[i*3+2]*b[2*3+k];
}

__global__ void k0_prep(const float* __restrict__ rots, const float* __restrict__ trans,
                        const float* __restrict__ intr, const float* __restrict__ prots,
                        const float* __restrict__ ptrans, const float* __restrict__ bda,
                        const float* __restrict__ W, float* __restrict__ ws,
                        float* __restrict__ dout) {
    int tid = blockIdx.x * 256 + threadIdx.x;
    int stride = gridDim.x * 256;
    // zero the BEV region of dout (depth region fully overwritten by k1)
    float4 z = {0.f, 0.f, 0.f, 0.f};
    for (int i = tid; i < BEV_ELEMS / 4; i += stride)
        *(float4*)(dout + 4 * (size_t)i) = z;
    unsigned short* wb = (unsigned short*)(ws + WS_WB);
    for (int i = tid; i < 128 * CIN; i += stride) {
        int o = i >> 9, c = i & 511;
        wb[i] = (o < NOUT) ? f2bf(W[o * CIN + c]) : (unsigned short)0;
    }
    if (blockIdx.x == 0 && threadIdx.x < B_ * N_) {
        #pragma clang fp contract(off)
        int t = threadIdx.x;
        int b = t / N_;
        double* X = (double*)(ws) + t * TDREC;
        double PR[9], Kd[9], Rd[9], Bd[9];
        for (int i = 0; i < 9; ++i) PR[i] = (double)prots[t * 9 + i];
        for (int i = 0; i < 9; ++i) Kd[i] = (double)intr[t * 9 + i];
        for (int i = 0; i < 9; ++i) Rd[i] = (double)rots[t * 9 + i];
        for (int i = 0; i < 9; ++i) Bd[i] = (double)bda[b * 9 + i];
        double iPR[9]; inv3d(PR, iPR);
        for (int i = 0; i < 9; ++i) X[i] = iPR[i];
        for (int i = 0; i < 3; ++i) X[9 + i] = (double)ptrans[t * 3 + i];
        double iK[9];  inv3d(Kd, iK);
        double comb[9]; mm3d(Rd, iK, comb);
        for (int i = 0; i < 9; ++i) X[12 + i] = comb[i];
        for (int i = 0; i < 3; ++i) X[21 + i] = (double)trans[t * 3 + i];
        for (int i = 0; i < 9; ++i) X[24 + i] = Bd[i];
    }
}

// ---------------- K0b: per-column quadratic geometry coefficients ----------------
// g_i(ds) for a ray column (b,n,h,w) is exactly quadratic in ds:
//   p_i = A_i + B_i*ds;  q = (p0*p2, p1*p2, p2);  r,g affine in q.
// Precompute the 9 f64 coeffs once per column; k2b evaluates 2-FMA Horner per g.
// (f64 algebraic refactor: perturbs g by ~1e-15 rel vs the validated chain,
//  while the passing f64-vs-f32-reference slack is ~1e-7 — safe.)
__global__ __launch_bounds__(256) void k0b_coef(float* __restrict__ ws) {
    #pragma clang fp contract(off)
    int i = blockIdx.x * 256 + threadIdx.x;      // 0..16895 == (b*FW+w)*96 + j
    int b = i / (FW * 96);
    int rem = i - b * (FW * 96);
    int w = rem / 96;
    int j = rem - w * 96;
    int n = j >> 4, h = j & 15;
    const double* T = (const double*)(ws) + (b * N_ + n) * TDREC;
    const double xs = (w == 43) ? 703.0 : (double)w * (703.0 / 43.0);
    const double ys = (double)(h * 17);
    const double u0 = xs - T[9];
    const double u1 = ys - T[10];
    double pA[3], pB[3];
    #pragma unroll
    for (int k = 0; k < 3; ++k) {
        pA[k] = (T[3*k]*u0 + T[3*k+1]*u1) - T[3*k+2]*T[11];
        pB[k] = T[3*k+2];
    }
    double q0c[3] = { pA[0]*pA[2], pA[0]*pB[2] + pB[0]*pA[2], pB[0]*pB[2] };
    double q1c[3] = { pA[1]*pA[2], pA[1]*pB[2] + pB[1]*pA[2], pB[1]*pB[2] };
    double q2c[3] = { pA[2], pB[2], 0.0 };
    double rc[3][3], gc[3][3];
    #pragma unroll
    for (int r = 0; r < 3; ++r)
        #pragma unroll
        for (int k = 0; k < 3; ++k)
            rc[r][k] = ((T[12+3*r]*q0c[k] + T[13+3*r]*q1c[k]) + T[14+3*r]*q2c[k])
                       + ((k == 0) ? T[21+r] : 0.0);
    #pragma unroll
    for (int g = 0; g < 3; ++g)
        #pragma unroll
        for (int k = 0; k < 3; ++k)
            gc[g][k] = (T[24+3*g]*rc[0][k] + T[25+3*g]*rc[1][k]) + T[26+3*g]*rc[2][k];
    double* dst = (double*)(ws) + WS_GC / 2 + (size_t)i * 9;
    #pragma unroll
    for (int t = 0; t < 9; ++t) dst[t] = gc[t / 3][t % 3];
}

// ---------------- K1: split-K bf16 MFMA GEMM + fused softmax epilogue ----------------
#define K1A   (64 * 72)                 // A tile shorts
#define K1T   (K1A + 128 * 72)          // shorts per (group,buf) tile = 13824
__global__ __launch_bounds__(512) void k1_gemm(const float* __restrict__ x,
                                               const float* __restrict__ bias,
                                               float* __restrict__ ws,
                                               float* __restrict__ dout) {
    __shared__ __align__(16) unsigned short smem[2][2][K1T];   // 110,592 B
    const int tid = threadIdx.x;
    const int grp = tid >> 8;             // K-half
    const int gtid = tid & 255;
    const int wave = gtid >> 6;           // wave within group (0..3)
    const int lane = tid & 63;
    const int l15 = lane & 15, quad = lane >> 4;
    const int bn = blockIdx.y;
    const int pixbase = blockIdx.x * 64;
    const float* xg = x + (size_t)bn * CIN * HW + pixbase;
    const unsigned short* wbg = (const unsigned short*)(ws + WS_WB);
    const int cpack = gtid >> 4;          // 0..15 (channel group of 4)
    const int pix4 = (gtid & 15) * 4;     // pixel group of 4
    const int wo  = gtid >> 3;            // weight-stage row (0..31)
    const int wsub = gtid & 7;            // weight-stage 16B sub-chunk
    const int ck0 = grp * 256;

    f32x4 acc[8] = {};
    float4 r0, r1, r2, r3;                // prefetched x tile (4c x 4pix)
    uint4  w4[4];                         // prefetched weight tile chunks

    {   // prologue: loads for this group's first K-step
        const float* src = xg + (size_t)(ck0 + 4 * cpack) * HW + pix4;
        r0 = *(const float4*)(src);
        r1 = *(const float4*)(src + HW);
        r2 = *(const float4*)(src + 2 * HW);
        r3 = *(const float4*)(src + 3 * HW);
        #pragma unroll
        for (int i = 0; i < 4; ++i)
            w4[i] = *(const uint4*)(wbg + (size_t)(wo + 32 * i) * CIN + ck0 + wsub * 8);
    }

    #pragma unroll
    for (int it = 0; it < 4; ++it) {
        const int buf = it & 1;
        unsigned short* sa = smem[grp][buf];            // [64][72]
        unsigned short* sb = smem[grp][buf] + K1A;      // [128][72]
        {   // store staged regs -> LDS (waits the prefetch vmcnt)
            const float* f0 = (const float*)&r0; const float* f1 = (const float*)&r1;
            const float* f2 = (const float*)&r2; const float* f3 = (const float*)&r3;
            #pragma unroll
            for (int i = 0; i < 4; ++i) {
                uint2 pk;
                pk.x = (unsigned)f2bf(f0[i]) | ((unsigned)f2bf(f1[i]) << 16);
                pk.y = (unsigned)f2bf(f2[i]) | ((unsigned)f2bf(f3[i]) << 16);
                *(uint2*)&sa[(pix4 + i) * 72 + 4 * cpack] = pk;
            }
            #pragma unroll
            for (int i = 0; i < 4; ++i)
                *(uint4*)&sb[(wo + 32 * i) * 72 + wsub * 8] = w4[i];
        }
        if (it < 3) {   // prefetch next K-step (overlaps MFMA phase below)
            const int ck = ck0 + (it + 1) * 64;
            const float* src = xg + (size_t)(ck + 4 * cpack) * HW + pix4;
            r0 = *(const float4*)(src);
            r1 = *(const float4*)(src + HW);
            r2 = *(const float4*)(src + 2 * HW);
            r3 = *(const float4*)(src + 3 * HW);
            #pragma unroll
            for (int i = 0; i < 4; ++i)
                w4[i] = *(const uint4*)(wbg + (size_t)(wo + 32 * i) * CIN + ck + wsub * 8);
        }
        __syncthreads();
        #pragma unroll
        for (int ks = 0; ks < 64; ks += 32) {
            const bf16x8 a = *(const bf16x8*)&sa[(wave * 16 + l15) * 72 + ks + quad * 8];
            #pragma unroll
            for (int nt = 0; nt < 8; ++nt) {
                const bf16x8 b = *(const bf16x8*)&sb[(nt * 16 + l15) * 72 + ks + quad * 8];
                acc[nt] = __builtin_amdgcn_mfma_f32_16x16x32_bf16(a, b, acc[nt], 0, 0, 0);
            }
        }
    }

    // ---- split-K reduce via LDS (tiles are dead; overlay). red[64][132] padded.
    __syncthreads();
    float* red = (float*)&smem[0][0][0];
    if (grp == 1) {
        #pragma unroll
        for (int nt = 0; nt < 8; ++nt)
            #pragma unroll
            for (int reg = 0; reg < 4; ++reg)
                red[(wave * 16 + quad * 4 + reg) * 132 + nt * 16 + l15] = acc[nt][reg];
    }
    __syncthreads();
    if (grp == 0) {
        #pragma unroll
        for (int nt = 0; nt < 8; ++nt)
            #pragma unroll
            for (int reg = 0; reg < 4; ++reg)
                acc[nt][reg] += red[(wave * 16 + quad * 4 + reg) * 132 + nt * 16 + l15];
    }
    __syncthreads();   // red dead; sred overlays same memory below

    // ---- epilogue (group 0 only): softmax + split store + p into LDS transpose.
    float* sred = (float*)&smem[0][0][0];
    const int b = bn / N_, n = bn - b * N_;
    if (grp == 0) {
        float bb[8];
        #pragma unroll
        for (int nt = 0; nt < 8; ++nt) {
            int o = nt * 16 + l15;
            bb[nt] = (o < NOUT) ? bias[o] : 0.0f;
        }
        float* ps = ws + WS_PS;
        float* fs = ws + WS_FS;
        #pragma unroll
        for (int reg = 0; reg < 4; ++reg) {
            int pixl = wave * 16 + quad * 4 + reg;
            int pix = pixbase + pixl;
            int h = pix / FW, w = pix - h * FW;
            size_t row = (size_t)(b * FW + w) * 96 + n * FH + h;
            float v[4]; float m = -INFINITY;
            #pragma unroll
            for (int nt = 0; nt < 4; ++nt) {
                v[nt] = acc[nt][reg] + bb[nt];
                if (nt * 16 + l15 < DEPN) m = fmaxf(m, v[nt]);
            }
            #pragma unroll
            for (int msk = 8; msk >= 1; msk >>= 1) m = fmaxf(m, __shfl_xor(m, msk, 64));
            float e[4], s = 0.0f;
            #pragma unroll
            for (int nt = 0; nt < 4; ++nt) {
                e[nt] = (nt * 16 + l15 < DEPN) ? expf(v[nt] - m) : 0.0f;
                s += e[nt];
            }
            #pragma unroll
            for (int msk = 8; msk >= 1; msk >>= 1) s += __shfl_xor(s, msk, 64);
            const float inv = 1.0f / s;
            #pragma unroll
            for (int nt = 0; nt < 4; ++nt) {
                int o = nt * 16 + l15;
                if (o < DEPN) {
                    float p = e[nt] * inv;
                    ps[row * 64 + o] = p;
                    sred[pixl * 65 + o] = p;
                } else fs[row * 64 + (o - DEPN)] = v[nt];   // o in 59..63 (nt==3 tail)
            }
            #pragma unroll
            for (int nt = 4; nt < 8; ++nt) {
                int o = nt * 16 + l15;
                if (o < NOUT) fs[row * 64 + (o - DEPN)] = acc[nt][reg] + bb[nt];
            }
        }
    }
    __syncthreads();
    // ---- coalesced depth write: 8 waves x o-rows, 256B contiguous per store
    const int wv8 = tid >> 6;
    for (int o = wv8; o < DEPN; o += 8)
        dout[DEPTH_OFF + ((size_t)bn * DEPN + o) * HW + pixbase + lane] = sred[lane * 65 + o];
}

// ---------------- K2b: Horner geometry + group-GEMM + direct BEV atomics ----------------
#define DQ2 16
__global__ __launch_bounds__(256) void k2b_geom(float* __restrict__ ws,
                                                float* __restrict__ dout) {
    __shared__ float sF[96][64];               // feats
    __shared__ float sP[DQ2][100];             // p tile, transposed, 16B-aligned rows
    __shared__ unsigned short sv16[DQ2 * 96];  // voxel id or 0xFFFF
    __shared__ __align__(16) double sG[96 * 9];// quadratic coeffs per column
    __shared__ int sflag[DQ2];
    const int tid = threadIdx.x;
    const int bw = blockIdx.x;
    const int b = bw / FW;
    const int dbase = blockIdx.y * DQ2;
    const int nd = min(DQ2, DEPN - dbase);

    {   // stage F + P(transposed, coalesced float4) + coeffs
        const float* fsrc = ws + WS_FS + (size_t)bw * (96 * 64);
        const float* psrc = ws + WS_PS + (size_t)bw * (96 * 64);
        for (int i = tid; i < 96 * 16; i += 256) {
            int j = i >> 4, c4 = (i & 15) * 4;
            *(float4*)&sF[j][c4] = *(const float4*)(fsrc + j * 64 + c4);
        }
        for (int i = tid; i < 96 * 4; i += 256) {
            int j = i >> 2, q = i & 3;
            const float4 p4 = *(const float4*)(psrc + j * 64 + dbase + 4 * q);
            sP[4 * q + 0][j] = p4.x; sP[4 * q + 1][j] = p4.y;
            sP[4 * q + 2][j] = p4.z; sP[4 * q + 3][j] = p4.w;
        }
        const double2* gsrc = (const double2*)((const double*)(ws) + WS_GC / 2
                                               + (size_t)bw * (96 * 9));
        for (int i = tid; i < 432; i += 256)
            ((double2*)sG)[i] = gsrc[i];
    }
    __syncthreads();

    {   // geometry: Horner evaluation of the validated f64 chain (k0b coeffs)
        const double BXY = (double)(-51.2000007629394531f);  // f32 value of BX-DX/2
        for (int idx = tid; idx < nd * 96; idx += 256) {
            int dl = idx / 96, j = idx - dl * 96;
            const double* G = &sG[j * 9];
            const double dsv = (double)(dbase + dl + 1);
            const double g0 = (G[2] * dsv + G[1]) * dsv + G[0];
            const double g1 = (G[5] * dsv + G[4]) * dsv + G[3];
            const double g2 = (G[8] * dsv + G[7]) * dsv + G[6];
            const double fx = floor((g0 - BXY) * 1.25);   // ==/0.8 bit-exact (1.25=1/0.8)
            const double fy = floor((g1 - BXY) * 1.25);
            const bool keep = (fx >= 0.0) & (fx < 128.0) & (fy >= 0.0) & (fy < 128.0) &
                              (g2 >= -10.0) & (g2 < 10.0);
            sv16[idx] = keep ? (unsigned short)((int)fx * NX + (int)fy) : (unsigned short)0xFFFF;
        }
    }
    __syncthreads();

    // flags: 256-thread parallel scan (16 threads/dl x 6 j each) + shfl combine
    {
        const int dl = tid >> 4, s = tid & 15;
        int u = -1, mix = 0;
        const int base = dl * 96 + s * 6;
        #pragma unroll
        for (int t = 0; t < 6; ++t) {
            int v = sv16[base + t];
            if (v != 0xFFFF) { if (u < 0) u = v; else if (v != u) mix = 1; }
        }
        #pragma unroll
        for (int msk = 1; msk < 16; msk <<= 1) {
            int uo = __shfl_xor(u, msk, 64);
            int mo = __shfl_xor(mix, msk, 64);
            mix = mix | mo | ((u >= 0 && uo >= 0 && uo != u) ? 1 : 0);
            u = (u < 0) ? uo : u;
        }
        if (s == 0 && dl < nd) sflag[dl] = mix ? -2 : u;
    }
    for (int idx = tid; idx < nd * 96; idx += 256) {
        if (sv16[idx] == 0xFFFF) {
            int dl = idx / 96, j = idx - dl * 96;
            sP[dl][j] = 0.0f;
        }
    }
    __syncthreads();

    // GEMM: C[d][c] = sum_j p[dl][j] * f[j][c]; thread = (dl, 4 channels).
    // float4 p loads + 4x unroll (batched LDS issues, shorter stall chains).
    const int dl = tid >> 4, ci = tid & 15;
    if (dl < nd && sflag[dl] >= 0) {
        float ax = 0.f, ay = 0.f, az = 0.f, aw = 0.f;
        for (int jj = 0; jj < 96; jj += 4) {
            const float4 pv = *(const float4*)&sP[dl][jj];
            const float4 f0 = *(const float4*)&sF[jj + 0][4 * ci];
            const float4 f1 = *(const float4*)&sF[jj + 1][4 * ci];
            const float4 f2 = *(const float4*)&sF[jj + 2][4 * ci];
            const float4 f3 = *(const float4*)&sF[jj + 3][4 * ci];
            ax = fmaf(pv.x, f0.x, ax); ay = fmaf(pv.x, f0.y, ay);
            az = fmaf(pv.x, f0.z, az); aw = fmaf(pv.x, f0.w, aw);
            ax = fmaf(pv.y, f1.x, ax); ay = fmaf(pv.y, f1.y, ay);
            az = fmaf(pv.y, f1.z, az); aw = fmaf(pv.y, f1.w, aw);
            ax = fmaf(pv.z, f2.x, ax); ay = fmaf(pv.z, f2.y, ay);
            az = fmaf(pv.z, f2.z, az); aw = fmaf(pv.z, f2.w, aw);
            ax = fmaf(pv.w, f3.x, ax); ay = fmaf(pv.w, f3.y, ay);
            az = fmaf(pv.w, f3.z, az); aw = fmaf(pv.w, f3.w, aw);
        }
        float* dst = dout + (((size_t)(b * CT + 4 * ci)) << 14) + sflag[dl];
        atomicAdd(dst,             ax);
        atomicAdd(dst + (1 << 14), ay);
        atomicAdd(dst + (2 << 14), az);
        atomicAdd(dst + (3 << 14), aw);
    }
    // rare per-point slow path for mixed groups
    for (int d2 = 0; d2 < nd; ++d2) {
        if (sflag[d2] == -2) {
            int c = tid & 63, g = tid >> 6;
            for (int jj = 0; jj < 24; ++jj) {
                int j = g * 24 + jj;
                int v = sv16[d2 * 96 + j];
                if (v != 0xFFFF)
                    atomicAdd(dout + (((size_t)(b * CT + c)) << 14) + v,
                              sP[d2][j] * sF[j][c]);
            }
        }
    }
}

// ---------------- launcher ----------------
extern "C" void kernel_launch(void* const* d_in, const int* in_sizes, int n_in,
                              void* d_out, int out_size, void* d_ws, size_t ws_size,
                              hipStream_t stream) {
    const float* x      = (const float*)d_in[0];
    const float* rots   = (const float*)d_in[1];
    const float* trans  = (const float*)d_in[2];
    const float* intr   = (const float*)d_in[3];
    const float* prots  = (const float*)d_in[4];
    const float* ptrans = (const float*)d_in[5];
    const float* bda    = (const float*)d_in[6];
    const float* W      = (const float*)d_in[7];
    const float* bias   = (const float*)d_in[8];
    float* out = (float*)d_out;
    float* ws  = (float*)d_ws;

    k0_prep<<<512, 256, 0, stream>>>(rots, trans, intr, prots, ptrans, bda, W, ws, out);
    k0b_coef<<<66, 256, 0, stream>>>(ws);           // 66*256 == 16896 columns exactly
    k1_gemm<<<dim3(HW / 64, B_ * N_), 512, 0, stream>>>(x, bias, ws, out);
    k2b_geom<<<dim3(B_ * FW, 4), 256, 0, stream>>>(ws, out);
}